// Round 5
// baseline (229.606 us; speedup 1.0000x reference)
//
#include <hip/hip_runtime.h>
#include <hip/hip_bf16.h>
#include <stdint.h>

// B=8, N=1024, D=256, fp32 in/out.
// R5: mega-kernel fuses scores GEMM (split-bf16 x3) + softmax + blend +
// entropy + route + out GEMM per 32-row strip. S / Pb never hit HBM.
// Scores phase reads fragments direct from global (L2-resident, XCD-pinned);
// LDS only for cross-wave reductions + C-layout -> A-layout P transpose.

#define NB 8
#define NN_ 1024
#define ND 256

typedef __bf16 bf16x8 __attribute__((ext_vector_type(8)));
typedef __bf16 bf16x4 __attribute__((ext_vector_type(4)));
typedef float f32x4 __attribute__((ext_vector_type(4)));

// ---------------- async global->LDS (16B per lane) -- used by xs mgemm ------
__device__ inline void gl_lds(const __bf16* g, __bf16* l) {
    auto gp = (const __attribute__((address_space(1))) uint32_t*)(uintptr_t)g;
    auto lp = (__attribute__((address_space(3))) uint32_t*)(uintptr_t)l;
    __builtin_amdgcn_global_load_lds(gp, lp, 16, 0, 0);
}

// ---------------- reductions (pos_kernel) ----------------
__device__ inline float wred_sum(float v) {
#pragma unroll
    for (int o = 32; o; o >>= 1) v += __shfl_xor(v, o, 64);
    return v;
}
__device__ inline float wred_max(float v) {
#pragma unroll
    for (int o = 32; o; o >>= 1) v = fmaxf(v, __shfl_xor(v, o, 64));
    return v;
}
__device__ inline float bred_sum(float v, float* red) {
    v = wred_sum(v);
    int w = threadIdx.x >> 6;
    __syncthreads();
    if ((threadIdx.x & 63) == 0) red[w] = v;
    __syncthreads();
    return red[0] + red[1] + red[2] + red[3];
}
__device__ inline float bred_max(float v, float* red) {
    v = wred_max(v);
    int w = threadIdx.x >> 6;
    __syncthreads();
    if ((threadIdx.x & 63) == 0) red[w] = v;
    __syncthreads();
    return fmaxf(fmaxf(red[0], red[1]), fmaxf(red[2], red[3]));
}

// ---------------- pos softmax ----------------
__global__ __launch_bounds__(256) void pos_kernel(
    const float* __restrict__ coords, const float* __restrict__ pos_emb,
    const float* __restrict__ p_temp, float* __restrict__ posS) {
    __shared__ float red[4];
    const int n = blockIdx.x;
    const int tid = threadIdx.x;
    const float pt = -fabsf(p_temp[0]);
    float pe[6];
#pragma unroll
    for (int c = 0; c < 6; ++c) pe[c] = pos_emb[n * 6 + c];
    const float* cr = coords + (long)n * NN_ * 6;
    float l[4];
#pragma unroll
    for (int j = 0; j < 4; ++j) {
        const int m = j * 256 + tid;
        const float2* cp = (const float2*)(cr + (long)m * 6);
        float2 c0 = cp[0], c1 = cp[1], c2 = cp[2];
        l[j] = pt * (c0.x * pe[0] + c0.y * pe[1] + c1.x * pe[2] +
                     c1.y * pe[3] + c2.x * pe[4] + c2.y * pe[5]);
    }
    float mx = fmaxf(fmaxf(l[0], l[1]), fmaxf(l[2], l[3]));
    mx = bred_max(mx, red);
    float e[4], s = 0.f;
#pragma unroll
    for (int j = 0; j < 4; ++j) { e[j] = expf(l[j] - mx); s += e[j]; }
    s = bred_sum(s, red);
    const float inv = 1.f / s;
#pragma unroll
    for (int j = 0; j < 4; ++j) posS[(long)n * NN_ + j * 256 + tid] = e[j] * inv;
}

// ---------------- fp32 -> bf16 hi/lo split ----------------
__global__ __launch_bounds__(256) void conv_split(
    const float* __restrict__ src, __bf16* __restrict__ hi,
    __bf16* __restrict__ lo, int n4) {
    int i = blockIdx.x * 256 + threadIdx.x;
    const int stride = gridDim.x * 256;
    for (; i < n4; i += stride) {
        float4 v = ((const float4*)src)[i];
        bf16x4 h, l;
        h[0] = (__bf16)v.x; l[0] = (__bf16)(v.x - (float)h[0]);
        h[1] = (__bf16)v.y; l[1] = (__bf16)(v.y - (float)h[1]);
        h[2] = (__bf16)v.z; l[2] = (__bf16)(v.z - (float)h[2]);
        h[3] = (__bf16)v.w; l[3] = (__bf16)(v.w - (float)h[3]);
        ((bf16x4*)hi)[i] = h;
        ((bf16x4*)lo)[i] = l;
    }
}

// ---------------- M_k = U^T diag(|S_k|) U  (symmetric), split hi/lo ---------
__global__ __launch_bounds__(256) void build_M(
    const float* __restrict__ U, const float* __restrict__ S1,
    const float* __restrict__ S2, __bf16* __restrict__ Mh,
    __bf16* __restrict__ Ml) {
    const int n = blockIdx.x, j = threadIdx.x;
    float a1 = 0.f, a2 = 0.f;
    for (int c = 0; c < ND; ++c) {
        const float un = U[c * ND + n];
        const float uj = U[c * ND + j];
        a1 = fmaf(fabsf(S1[c]) * un, uj, a1);
        a2 = fmaf(fabsf(S2[c]) * un, uj, a2);
    }
    const __bf16 h1 = (__bf16)a1, h2 = (__bf16)a2;
    Mh[n * ND + j] = h1;            Ml[n * ND + j] = (__bf16)(a1 - (float)h1);
    Mh[65536 + n * ND + j] = h2;    Ml[65536 + n * ND + j] = (__bf16)(a2 - (float)h2);
}

// ---------------- y: emit yt (bf16 transposed) + y hi/lo split --------------
__global__ __launch_bounds__(256) void prep_y(
    const float* __restrict__ y, __bf16* __restrict__ yt,
    __bf16* __restrict__ Yh, __bf16* __restrict__ Yl) {
    __shared__ __bf16 t[64][72];
    const int b = blockIdx.z;
    const int m0 = blockIdx.x * 64, d0 = blockIdx.y * 64;
    const int tid = threadIdx.x;
    const int c = tid & 15;
    const int r = tid >> 4;
#pragma unroll
    for (int p = 0; p < 4; ++p) {
        const int row = r + p * 16;
        const long gi = ((long)b * NN_ + m0 + row) * ND + d0 + c * 4;
        float4 v = *(const float4*)(y + gi);
        bf16x4 h, l;
        h[0] = (__bf16)v.x; l[0] = (__bf16)(v.x - (float)h[0]);
        h[1] = (__bf16)v.y; l[1] = (__bf16)(v.y - (float)h[1]);
        h[2] = (__bf16)v.z; l[2] = (__bf16)(v.z - (float)h[2]);
        h[3] = (__bf16)v.w; l[3] = (__bf16)(v.w - (float)h[3]);
        *(bf16x4*)(Yh + gi) = h;
        *(bf16x4*)(Yl + gi) = l;
        t[c * 4 + 0][row] = h[0]; t[c * 4 + 1][row] = h[1];
        t[c * 4 + 2][row] = h[2]; t[c * 4 + 3][row] = h[3];
    }
    __syncthreads();
#pragma unroll
    for (int p = 0; p < 4; ++p) {
        const int d = r + p * 16;
        bf16x4 o;
        o[0] = t[d][c * 4 + 0]; o[1] = t[d][c * 4 + 1];
        o[2] = t[d][c * 4 + 2]; o[3] = t[d][c * 4 + 3];
        *(bf16x4*)(yt + ((long)b * ND + d0 + d) * NN_ + m0 + c * 4) = o;
    }
}

// ---------------- MFMA GEMM (xs = x @ M_k), global_load_lds staged ----------
template <int BN, bool SPLIT, int OUTM>
__global__ __launch_bounds__(256) void mgemm(
    const __bf16* __restrict__ Ah, const __bf16* __restrict__ Al,
    const __bf16* __restrict__ Bh, const __bf16* __restrict__ Bl,
    float* __restrict__ C, __bf16* __restrict__ Ch, __bf16* __restrict__ Cl,
    int M, int N, int K,
    long sA1, long sA2, int divA, long sB1, int divB, long sC, float alpha) {
    constexpr int BM = 128, BK = 32;
    constexpr int NBUF = SPLIT ? 2 : 1;
    constexpr int NF = BN / 32;
    __shared__ __bf16 As[NBUF * BM * BK];
    __shared__ __bf16 Bs[NBUF * BN * BK];

    const int z = blockIdx.z;
    const long aoff = (long)(z / divA) * sA1 + (long)(z % divA) * sA2;
    const long boff = (long)(z / divB) * sB1;
    Ah += aoff; if (SPLIT) Al += aoff;
    Bh += boff; if (SPLIT) Bl += boff;

    const int tid = threadIdx.x;
    const int bm = blockIdx.y * BM, bn = blockIdx.x * BN;
    const int wave = tid >> 6, lane = tid & 63;
    const int wm = wave >> 1, wn = wave & 1;
    const int quad = lane >> 4, l16 = lane & 15;

    f32x4 acc[4][NF];
#pragma unroll
    for (int i = 0; i < 4; ++i)
#pragma unroll
        for (int j = 0; j < NF; ++j) acc[i][j] = (f32x4){0.f, 0.f, 0.f, 0.f};

    const int srow = lane >> 2;
    const int slot = lane & 3;

    for (int k0 = 0; k0 < K; k0 += BK) {
        __syncthreads();
#pragma unroll
        for (int i = 0; i < 2; ++i) {
            const int r0 = wave * 32 + i * 16;
            const int row = r0 + srow;
            const int chunk = slot ^ ((row >> 1) & 3);
            const long g = (long)(bm + row) * K + k0 + chunk * 8;
            gl_lds(Ah + g, &As[r0 * 32]);
            if (SPLIT) gl_lds(Al + g, &As[BM * BK + r0 * 32]);
        }
        if (BN == 128) {
#pragma unroll
            for (int i = 0; i < 2; ++i) {
                const int r0 = wave * 32 + i * 16;
                const int row = r0 + srow;
                const int chunk = slot ^ ((row >> 1) & 3);
                const long g = (long)(bn + row) * K + k0 + chunk * 8;
                gl_lds(Bh + g, &Bs[r0 * 32]);
                if (SPLIT) gl_lds(Bl + g, &Bs[BN * BK + r0 * 32]);
            }
        } else {
            const int r0 = wave * 16;
            const int row = r0 + srow;
            const int chunk = slot ^ ((row >> 1) & 3);
            const long g = (long)(bn + row) * K + k0 + chunk * 8;
            gl_lds(Bh + g, &Bs[r0 * 32]);
            if (SPLIT) gl_lds(Bl + g, &Bs[BN * BK + r0 * 32]);
        }
        __syncthreads();

        bf16x8 a_h[4], a_l[4], b_h[NF], b_l[NF];
#pragma unroll
        for (int mi = 0; mi < 4; ++mi) {
            const int row = wm * 64 + mi * 16 + l16;
            const int off = row * 32 + ((quad ^ ((row >> 1) & 3)) * 8);
            a_h[mi] = *(const bf16x8*)&As[off];
            if (SPLIT) a_l[mi] = *(const bf16x8*)&As[BM * BK + off];
        }
#pragma unroll
        for (int ni = 0; ni < NF; ++ni) {
            const int row = wn * (BN / 2) + ni * 16 + l16;
            const int off = row * 32 + ((quad ^ ((row >> 1) & 3)) * 8);
            b_h[ni] = *(const bf16x8*)&Bs[off];
            if (SPLIT) b_l[ni] = *(const bf16x8*)&Bs[BN * BK + off];
        }
#pragma unroll
        for (int mi = 0; mi < 4; ++mi)
#pragma unroll
            for (int ni = 0; ni < NF; ++ni) {
                acc[mi][ni] = __builtin_amdgcn_mfma_f32_16x16x32_bf16(
                    a_h[mi], b_h[ni], acc[mi][ni], 0, 0, 0);
                if (SPLIT) {
                    acc[mi][ni] = __builtin_amdgcn_mfma_f32_16x16x32_bf16(
                        a_h[mi], b_l[ni], acc[mi][ni], 0, 0, 0);
                    acc[mi][ni] = __builtin_amdgcn_mfma_f32_16x16x32_bf16(
                        a_l[mi], b_h[ni], acc[mi][ni], 0, 0, 0);
                }
            }
    }

    C += (long)z * sC; Ch += (long)z * sC; Cl += (long)z * sC;
#pragma unroll
    for (int mi = 0; mi < 4; ++mi) {
        const int row0 = bm + wm * 64 + mi * 16 + quad * 4;
#pragma unroll
        for (int ni = 0; ni < NF; ++ni) {
            const int col = bn + wn * (BN / 2) + ni * 16 + l16;
#pragma unroll
            for (int r = 0; r < 4; ++r) {
                const float v = acc[mi][ni][r] * alpha;
                const long idx = (long)(row0 + r) * N + col;
                if (OUTM == 0) {
                    C[idx] = v;
                } else {
                    const __bf16 h = (__bf16)v;
                    Ch[idx] = h;
                    Cl[idx] = (__bf16)(v - (float)h);
                }
            }
        }
    }
}

// ---------------- MEGA: scores + softmax + blend + entropy + route + out ----
// Block = 256 thr (4 waves), handles b = blockIdx&7, rows n0..n0+31, both
// branches, all 1024 cols. Wave w owns cols [w*256, w*256+256).
// LDS: Pl [32][1032] bf16 (selected attn, padded) + red 3x[4][2][32] f32.
__global__ __launch_bounds__(256, 1) void mega_kernel(
    const __bf16* __restrict__ XSh, const __bf16* __restrict__ XSl,
    const __bf16* __restrict__ Yh, const __bf16* __restrict__ Yl,
    const __bf16* __restrict__ yt, const float* __restrict__ pos,
    const float* __restrict__ gating, const float* __restrict__ h_temp,
    float* __restrict__ heat, float* __restrict__ out) {
    extern __shared__ char smem[];
    __bf16* Pl  = (__bf16*)smem;                  // 32 x 1032 = 66048 B
    float* red0 = (float*)(smem + 66048);         // [4][2][32]
    float* red1 = red0 + 256;
    float* red2 = red1 + 256;

    const int b  = blockIdx.x & 7;
    const int n0 = (blockIdx.x >> 3) * 32;
    const int tid = threadIdx.x;
    const int wave = tid >> 6, lane = tid & 63;
    const int quad = lane >> 4, l16 = lane & 15;
    const int wcol = wave * 256;

    const __bf16* Ahp = XSh + ((long)b * NN_ + n0) * ND;
    const __bf16* Alp = XSl + ((long)b * NN_ + n0) * ND;
    const __bf16* Bhp = Yh + ((long)b * NN_ + wcol) * ND;
    const __bf16* Blp = Yl + ((long)b * NN_ + wcol) * ND;

    f32x4 acc[2][2][16];
#pragma unroll
    for (int br = 0; br < 2; ++br)
#pragma unroll
        for (int mi = 0; mi < 2; ++mi)
#pragma unroll
            for (int ni = 0; ni < 16; ++ni)
                acc[br][mi][ni] = (f32x4){0.f, 0.f, 0.f, 0.f};

    // ---- scores K-loop: direct-global fragments, no LDS, no barriers ----
    for (int k0 = 0; k0 < ND; k0 += 32) {
        bf16x8 ah[2][2], al[2][2];
#pragma unroll
        for (int br = 0; br < 2; ++br)
#pragma unroll
            for (int mi = 0; mi < 2; ++mi) {
                const long o = (long)br * (NB * NN_ * ND) +
                               (long)(mi * 16 + l16) * ND + k0 + quad * 8;
                ah[br][mi] = *(const bf16x8*)(Ahp + o);
                al[br][mi] = *(const bf16x8*)(Alp + o);
            }
#pragma unroll
        for (int ni = 0; ni < 16; ++ni) {
            const long o = (long)(ni * 16 + l16) * ND + k0 + quad * 8;
            bf16x8 bh = *(const bf16x8*)(Bhp + o);
            bf16x8 bl = *(const bf16x8*)(Blp + o);
#pragma unroll
            for (int br = 0; br < 2; ++br)
#pragma unroll
                for (int mi = 0; mi < 2; ++mi) {
                    acc[br][mi][ni] = __builtin_amdgcn_mfma_f32_16x16x32_bf16(
                        ah[br][mi], bh, acc[br][mi][ni], 0, 0, 0);
                    acc[br][mi][ni] = __builtin_amdgcn_mfma_f32_16x16x32_bf16(
                        ah[br][mi], bl, acc[br][mi][ni], 0, 0, 0);
                    acc[br][mi][ni] = __builtin_amdgcn_mfma_f32_16x16x32_bf16(
                        al[br][mi], bh, acc[br][mi][ni], 0, 0, 0);
                }
        }
    }

    // ---- scale logits ----
#pragma unroll
    for (int br = 0; br < 2; ++br)
#pragma unroll
        for (int mi = 0; mi < 2; ++mi)
#pragma unroll
            for (int ni = 0; ni < 16; ++ni)
#pragma unroll
                for (int rr = 0; rr < 4; ++rr)
                    acc[br][mi][ni][rr] *= 0.0625f;

    // ---- row max ----
    float mx[2][2][4];
#pragma unroll
    for (int br = 0; br < 2; ++br)
#pragma unroll
        for (int mi = 0; mi < 2; ++mi)
#pragma unroll
            for (int rr = 0; rr < 4; ++rr) {
                float m = -3.4e38f;
#pragma unroll
                for (int ni = 0; ni < 16; ++ni) m = fmaxf(m, acc[br][mi][ni][rr]);
                mx[br][mi][rr] = m;
            }
#pragma unroll
    for (int o = 1; o < 16; o <<= 1)
#pragma unroll
        for (int br = 0; br < 2; ++br)
#pragma unroll
            for (int mi = 0; mi < 2; ++mi)
#pragma unroll
                for (int rr = 0; rr < 4; ++rr)
                    mx[br][mi][rr] = fmaxf(mx[br][mi][rr],
                                           __shfl_xor(mx[br][mi][rr], o, 64));
    if (l16 == 0)
#pragma unroll
        for (int br = 0; br < 2; ++br)
#pragma unroll
            for (int mi = 0; mi < 2; ++mi)
#pragma unroll
                for (int rr = 0; rr < 4; ++rr)
                    red0[(wave * 2 + br) * 32 + mi * 16 + quad * 4 + rr] = mx[br][mi][rr];
    __syncthreads();
#pragma unroll
    for (int br = 0; br < 2; ++br)
#pragma unroll
        for (int mi = 0; mi < 2; ++mi)
#pragma unroll
            for (int rr = 0; rr < 4; ++rr) {
                const int ri = mi * 16 + quad * 4 + rr;
                float m = red0[(0 * 2 + br) * 32 + ri];
                m = fmaxf(m, red0[(1 * 2 + br) * 32 + ri]);
                m = fmaxf(m, red0[(2 * 2 + br) * 32 + ri]);
                m = fmaxf(m, red0[(3 * 2 + br) * 32 + ri]);
                mx[br][mi][rr] = m;
            }

    // ---- exp (in place) + row sum ----
    float sm[2][2][4];
#pragma unroll
    for (int br = 0; br < 2; ++br)
#pragma unroll
        for (int mi = 0; mi < 2; ++mi)
#pragma unroll
            for (int rr = 0; rr < 4; ++rr) {
                float s = 0.f;
#pragma unroll
                for (int ni = 0; ni < 16; ++ni) {
                    const float e = __expf(acc[br][mi][ni][rr] - mx[br][mi][rr]);
                    acc[br][mi][ni][rr] = e;
                    s += e;
                }
                sm[br][mi][rr] = s;
            }
#pragma unroll
    for (int o = 1; o < 16; o <<= 1)
#pragma unroll
        for (int br = 0; br < 2; ++br)
#pragma unroll
            for (int mi = 0; mi < 2; ++mi)
#pragma unroll
                for (int rr = 0; rr < 4; ++rr)
                    sm[br][mi][rr] += __shfl_xor(sm[br][mi][rr], o, 64);
    if (l16 == 0)
#pragma unroll
        for (int br = 0; br < 2; ++br)
#pragma unroll
            for (int mi = 0; mi < 2; ++mi)
#pragma unroll
                for (int rr = 0; rr < 4; ++rr)
                    red1[(wave * 2 + br) * 32 + mi * 16 + quad * 4 + rr] = sm[br][mi][rr];
    __syncthreads();
    float inv[2][2][4];
#pragma unroll
    for (int br = 0; br < 2; ++br)
#pragma unroll
        for (int mi = 0; mi < 2; ++mi)
#pragma unroll
            for (int rr = 0; rr < 4; ++rr) {
                const int ri = mi * 16 + quad * 4 + rr;
                const float s = red1[(0 * 2 + br) * 32 + ri] + red1[(1 * 2 + br) * 32 + ri] +
                                red1[(2 * 2 + br) * 32 + ri] + red1[(3 * 2 + br) * 32 + ri];
                inv[br][mi][rr] = 1.f / s;
            }

    // ---- blend with pos + entropy (a stored in place of e) ----
    const float g = 1.f / (1.f + __expf(-gating[0]));
    const float cg = 1.f - g;
    float ent[2][2][4];
#pragma unroll
    for (int br = 0; br < 2; ++br)
#pragma unroll
        for (int mi = 0; mi < 2; ++mi)
#pragma unroll
            for (int rr = 0; rr < 4; ++rr) ent[br][mi][rr] = 0.f;
#pragma unroll
    for (int mi = 0; mi < 2; ++mi)
#pragma unroll
        for (int ni = 0; ni < 16; ++ni)
#pragma unroll
            for (int rr = 0; rr < 4; ++rr) {
                const int ri = mi * 16 + quad * 4 + rr;
                const float pv = pos[(long)(n0 + ri) * NN_ + wcol + ni * 16 + l16];
#pragma unroll
                for (int br = 0; br < 2; ++br) {
                    const float a = cg * acc[br][mi][ni][rr] * inv[br][mi][rr] + g * pv;
                    acc[br][mi][ni][rr] = a;
                    ent[br][mi][rr] -= a * __logf(a + 1e-8f);
                }
            }
#pragma unroll
    for (int o = 1; o < 16; o <<= 1)
#pragma unroll
        for (int br = 0; br < 2; ++br)
#pragma unroll
            for (int mi = 0; mi < 2; ++mi)
#pragma unroll
                for (int rr = 0; rr < 4; ++rr)
                    ent[br][mi][rr] += __shfl_xor(ent[br][mi][rr], o, 64);
    if (l16 == 0)
#pragma unroll
        for (int br = 0; br < 2; ++br)
#pragma unroll
            for (int mi = 0; mi < 2; ++mi)
#pragma unroll
                for (int rr = 0; rr < 4; ++rr)
                    red2[(wave * 2 + br) * 32 + mi * 16 + quad * 4 + rr] = ent[br][mi][rr];
    __syncthreads();

    // ---- route + heat + write selected P (bf16) into LDS ----
    const float ht = h_temp[0];
    float fsel[2][4];
#pragma unroll
    for (int mi = 0; mi < 2; ++mi)
#pragma unroll
        for (int rr = 0; rr < 4; ++rr) {
            const int ri = mi * 16 + quad * 4 + rr;
            const float e0 = red2[0 * 32 + ri] + red2[2 * 32 + ri] +
                             red2[4 * 32 + ri] + red2[6 * 32 + ri];
            const float e1 = red2[1 * 32 + ri] + red2[3 * 32 + ri] +
                             red2[5 * 32 + ri] + red2[7 * 32 + ri];
            const float hm0 = 2.f - 2.f / (1.f + __expf(-ht * e0));
            const float hm1 = 2.f - 2.f / (1.f + __expf(-ht * e1));
            const bool fg = (hm0 >= hm1);
            fsel[mi][rr] = fg ? 1.f : 0.f;
            if (wave == 0 && l16 == 0)
                heat[(long)b * NN_ + n0 + ri] = fg ? hm0 : hm1;
        }
#pragma unroll
    for (int mi = 0; mi < 2; ++mi)
#pragma unroll
        for (int ni = 0; ni < 16; ++ni)
#pragma unroll
            for (int rr = 0; rr < 4; ++rr) {
                const int ri = mi * 16 + quad * 4 + rr;
                const float v = fsel[mi][rr] != 0.f ? acc[0][mi][ni][rr]
                                                    : acc[1][mi][ni][rr];
                Pl[ri * 1032 + wcol + ni * 16 + l16] = (__bf16)v;
            }
    __syncthreads();

    // ---- fused out GEMM: out[32 x 256] = P(LDS) @ yt^T ----
    f32x4 oacc[2][4];
#pragma unroll
    for (int mi = 0; mi < 2; ++mi)
#pragma unroll
        for (int nd = 0; nd < 4; ++nd) oacc[mi][nd] = (f32x4){0.f, 0.f, 0.f, 0.f};
    const __bf16* Bo = yt + ((long)b * ND + wave * 64) * NN_;
    for (int k0 = 0; k0 < NN_; k0 += 32) {
        bf16x8 pa[2];
#pragma unroll
        for (int mi = 0; mi < 2; ++mi)
            pa[mi] = *(const bf16x8*)&Pl[(mi * 16 + l16) * 1032 + k0 + quad * 8];
#pragma unroll
        for (int nd = 0; nd < 4; ++nd) {
            bf16x8 bo = *(const bf16x8*)(Bo + (long)(nd * 16 + l16) * NN_ + k0 + quad * 8);
#pragma unroll
            for (int mi = 0; mi < 2; ++mi)
                oacc[mi][nd] = __builtin_amdgcn_mfma_f32_16x16x32_bf16(
                    pa[mi], bo, oacc[mi][nd], 0, 0, 0);
        }
    }
#pragma unroll
    for (int mi = 0; mi < 2; ++mi)
#pragma unroll
        for (int nd = 0; nd < 4; ++nd)
#pragma unroll
            for (int r = 0; r < 4; ++r)
                out[((long)b * NN_ + n0 + mi * 16 + quad * 4 + r) * ND +
                    wave * 64 + nd * 16 + l16] = oacc[mi][nd][r];
}

extern "C" void kernel_launch(void* const* d_in, const int* in_sizes, int n_in,
                              void* d_out, int out_size, void* d_ws, size_t ws_size,
                              hipStream_t stream) {
    const float* x      = (const float*)d_in[0];
    const float* y      = (const float*)d_in[1];
    const float* coords = (const float*)d_in[2];
    const float* U      = (const float*)d_in[3];
    const float* S1p    = (const float*)d_in[4];
    const float* S2p    = (const float*)d_in[5];
    const float* gating = (const float*)d_in[6];
    const float* h_temp = (const float*)d_in[7];
    const float* p_temp = (const float*)d_in[8];
    const float* pos_emb= (const float*)d_in[9];

    float* out  = (float*)d_out;
    float* heat = out + (long)NB * NN_ * ND;

    // workspace (~40.5 MB)
    char* ws = (char*)d_ws;
    const long MB = 1 << 20;
    float*  pos = (float*)(ws);               // 4 MB
    __bf16* Xh  = (__bf16*)(ws + 4 * MB);     // 4 MB
    __bf16* Xl  = (__bf16*)(ws + 8 * MB);     // 4 MB
    __bf16* XSh = (__bf16*)(ws + 12 * MB);    // 8 MB [2][8192][256]
    __bf16* XSl = (__bf16*)(ws + 20 * MB);    // 8 MB
    __bf16* yt  = (__bf16*)(ws + 28 * MB);    // 4 MB [8][256][1024]
    __bf16* Yh  = (__bf16*)(ws + 32 * MB);    // 4 MB
    __bf16* Yl  = (__bf16*)(ws + 36 * MB);    // 4 MB
    __bf16* Mh  = (__bf16*)(ws + 40 * MB);    // 256 KB [2][256][256]
    __bf16* Ml  = Mh + 2 * 65536;             // 256 KB

    const long ND2 = (long)NN_ * ND;   // 262144
    const long BND = (long)NB * ND2;   // 2097152

    pos_kernel<<<dim3(NN_), 256, 0, stream>>>(coords, pos_emb, p_temp, pos);
    conv_split<<<dim3(2048), 256, 0, stream>>>(x, Xh, Xl, (int)(BND / 4));
    prep_y<<<dim3(16, 4, NB), 256, 0, stream>>>(y, yt, Yh, Yl);
    build_M<<<dim3(ND), ND, 0, stream>>>(U, S1p, S2p, Mh, Ml);

    // xs_k = x @ M_k  (z=k) -> XS [2][8192][256]
    mgemm<64, true, 1><<<dim3(4, 64, 2), 256, 0, stream>>>(
        Xh, Xl, Mh, Ml, nullptr, XSh, XSl, NB * NN_, ND, ND,
        0, 0, 1, 65536, 1, BND, 1.0f);

    // mega: scores + softmax + blend + entropy + route + out
    hipFuncSetAttribute((const void*)mega_kernel,
                        hipFuncAttributeMaxDynamicSharedMemorySize, 69632);
    mega_kernel<<<dim3(256), 256, 69632, stream>>>(
        XSh, XSl, Yh, Yl, yt, pos, gating, h_temp, heat, out);

    (void)in_sizes; (void)n_in; (void)out_size; (void)ws_size;
}